// Round 15
// baseline (99.627 us; speedup 1.0000x reference)
//
#include <hip/hip_runtime.h>
#include <hip/hip_bf16.h>

typedef __attribute__((ext_vector_type(8))) short bf16x8;
typedef __attribute__((ext_vector_type(4))) float f32x4;
typedef __attribute__((ext_vector_type(16))) float f32x16;
typedef __attribute__((ext_vector_type(8))) unsigned short ushort8v;
typedef __attribute__((ext_vector_type(4))) unsigned short ushort4v;

#define MFMA16(a, b, c) __builtin_amdgcn_mfma_f32_16x16x32_bf16((a), (b), (c), 0, 0, 0)
#define MFMA32(a, b, c) __builtin_amdgcn_mfma_f32_32x32x16_bf16((a), (b), (c), 0, 0, 0)

// HW packed f32->bf16 (src0 -> low16, src1 -> high16, RNE)
__device__ __forceinline__ unsigned int cvtpk(float a, float b) {
  unsigned int r;
  asm("v_cvt_pk_bf16_f32 %0, %1, %2" : "=v"(r) : "v"(a), "v"(b));
  return r;
}
__device__ __forceinline__ unsigned short f2bf(float f) {
  return (unsigned short)cvtpk(f, f);
}

// ---------------- all transposes in one kernel ----------------
__global__ __launch_bounds__(256) void transpose_all_kernel(
    const float* __restrict__ x, const float* __restrict__ ctx,
    const float* __restrict__ Wq, const float* __restrict__ Wkv,
    const float* __restrict__ Wo, unsigned short* __restrict__ xt,
    unsigned short* __restrict__ ct, unsigned short* __restrict__ Wqt,
    unsigned short* __restrict__ Wkvt, unsigned short* __restrict__ Wot) {
  __shared__ float tile[64][33];
  int z = blockIdx.z;
  const float* in;
  unsigned short* out;
  int C;
  if (z < 4)      { in = x + (size_t)z * 512 * 2048;         out = xt + (size_t)z * 2048 * 512;        C = 2048; }
  else if (z < 8) { in = ctx + (size_t)(z - 4) * 512 * 2048; out = ct + (size_t)(z - 4) * 2048 * 512;  C = 2048; }
  else if (z == 8) { in = Wq;  out = Wqt;  C = 512; }
  else if (z == 9) { in = Wkv; out = Wkvt; C = 1024; }
  else             { in = Wo;  out = Wot;  C = 512; }
  int c0 = blockIdx.x * 32;
  if (c0 >= C) return;
  int r0 = blockIdx.y * 64;
  int tid = threadIdx.x, cl = tid & 31, rl = tid >> 5;
#pragma unroll
  for (int k = 0; k < 8; ++k)
    tile[rl + 8 * k][cl] = in[(size_t)(r0 + rl + 8 * k) * C + c0 + cl];
  __syncthreads();
  int c = tid >> 3, rc = (tid & 7) * 8;
  union { unsigned int wd[4]; ushort8v v; } p;
#pragma unroll
  for (int jj = 0; jj < 4; ++jj)
    p.wd[jj] = cvtpk(tile[rc + 2 * jj][c], tile[rc + 2 * jj + 1][c]);
  *(ushort8v*)&out[(size_t)(c0 + c) * 512 + r0 + rc] = p.v;
}

// ---------------- shared NT-GEMM core, 128x128 tile, global_load_lds staging ----------------
__device__ __forceinline__ void gemm_acc128(
    const unsigned short* __restrict__ A, const unsigned short* __restrict__ Bt,
    int l0, int o0, f32x4 acc[4][4],
    unsigned short* As, unsigned short* Bs) {
  int tid = threadIdx.x, lane = tid & 63, wv = tid >> 6;
  int wl = wv >> 1, wo = wv & 1, lg = lane >> 4, lr = lane & 15;
  int r8 = lane >> 3, gc = (lane & 7) ^ r8;
  const unsigned short* ga = A + (size_t)(l0 + wv * 32 + r8) * 512 + gc * 8;
  const unsigned short* gb = Bt + (size_t)(o0 + wv * 32 + r8) * 512 + gc * 8;
  int rowbA[4], rswA[4], rowbB[4], rswB[4];
#pragma unroll
  for (int f = 0; f < 4; ++f) {
    int r = wl * 64 + f * 16 + lr;
    rowbA[f] = (r >> 3) * 1040 + (r & 7) * 128;
    rswA[f] = (r & 7) << 4;
    int rb = wo * 64 + f * 16 + lr;
    rowbB[f] = (rb >> 3) * 1040 + (rb & 7) * 128;
    rswB[f] = (rb & 7) << 4;
  }
  const char* aC = (const char*)As;
  const char* bC = (const char*)Bs;
  for (int kb = 0; kb < 512; kb += 64) {
#pragma unroll
    for (int j = 0; j < 4; ++j) {
      __builtin_amdgcn_global_load_lds(
          (const __attribute__((address_space(1))) void*)(ga + (size_t)(j * 8) * 512 + kb),
          (__attribute__((address_space(3))) void*)(As + (wv * 4 + j) * 520), 16, 0, 0);
      __builtin_amdgcn_global_load_lds(
          (const __attribute__((address_space(1))) void*)(gb + (size_t)(j * 8) * 512 + kb),
          (__attribute__((address_space(3))) void*)(Bs + (wv * 4 + j) * 520), 16, 0, 0);
    }
    __syncthreads();
#pragma unroll
    for (int kc = 0; kc < 2; ++kc) {
      bf16x8 af[4], bfr[4];
#pragma unroll
      for (int mf = 0; mf < 4; ++mf)
        af[mf] = *(const bf16x8*)(aC + rowbA[mf] + (((4 * kc + lg) << 4) ^ rswA[mf]));
#pragma unroll
      for (int nf = 0; nf < 4; ++nf)
        bfr[nf] = *(const bf16x8*)(bC + rowbB[nf] + (((4 * kc + lg) << 4) ^ rswB[nf]));
#pragma unroll
      for (int mf = 0; mf < 4; ++mf)
#pragma unroll
        for (int nf = 0; nf < 4; ++nf)
          acc[mf][nf] = MFMA16(af[mf], bfr[nf], acc[mf][nf]);
    }
    __syncthreads();
  }
}

// Merged Q + KV projection.
__global__ __launch_bounds__(256) void gemm_qkv_kernel(
    const unsigned short* __restrict__ xt, const unsigned short* __restrict__ ct,
    const unsigned short* __restrict__ Wqt, const unsigned short* __restrict__ Wkvt,
    unsigned short* __restrict__ Qb, unsigned short* __restrict__ K,
    unsigned short* __restrict__ Vt) {
  __shared__ unsigned short As[8320];
  __shared__ unsigned short Bs[8320];
  f32x4 acc[4][4] = {};
  int l0 = blockIdx.x * 128;
  int yy = blockIdx.y;
  const unsigned short* A;
  const unsigned short* Bt;
  int o0;
  if (yy < 4) { A = xt; Bt = Wqt; o0 = yy * 128; }
  else        { A = ct; Bt = Wkvt; o0 = (yy - 4) * 128; }
  gemm_acc128(A, Bt, l0, o0, acc, As, Bs);
  int lane = threadIdx.x & 63, wave = threadIdx.x >> 6;
  int wl = wave >> 1, wo = wave & 1, lg = lane >> 4, lr = lane & 15;
  if (yy < 4) {
    const float qs = 0.18033688011112042f;  // 0.125 * log2(e)
#pragma unroll
    for (int mf = 0; mf < 4; ++mf)
#pragma unroll
      for (int nf = 0; nf < 4; ++nf)
#pragma unroll
        for (int r = 0; r < 4; ++r) {
          int row = l0 + wl * 64 + mf * 16 + 4 * lg + r;
          int col = o0 + wo * 64 + nf * 16 + lr;
          Qb[(size_t)row * 512 + col] = f2bf(acc[mf][nf][r] * qs);
        }
  } else if (o0 < 512) {
#pragma unroll
    for (int mf = 0; mf < 4; ++mf)
#pragma unroll
      for (int nf = 0; nf < 4; ++nf)
#pragma unroll
        for (int r = 0; r < 4; ++r) {
          int row = l0 + wl * 64 + mf * 16 + 4 * lg + r;
          int col = o0 + wo * 64 + nf * 16 + lr;
          K[(size_t)row * 512 + col] = f2bf(acc[mf][nf][r]);
        }
  } else {
    int b = l0 >> 11;
#pragma unroll
    for (int mf = 0; mf < 4; ++mf)
#pragma unroll
      for (int nf = 0; nf < 4; ++nf) {
        int m0v = (l0 & 2047) + wl * 64 + mf * 16 + 4 * lg;
        int msw = (m0v & ~12) | ((m0v & 4) << 1) | ((m0v & 8) >> 1);  // swap bits 2,3
        int oh = (o0 - 512) + wo * 64 + nf * 16 + lr;
        int h = oh >> 6, d = oh & 63;
        ushort4v pk;
#pragma unroll
        for (int r = 0; r < 4; ++r) pk[r] = f2bf(acc[mf][nf][r]);
        *(ushort4v*)&Vt[(size_t)((b * 8 + h) * 64 + d) * 2048 + msw] = pk;
      }
  }
}

// Out projection.
__global__ __launch_bounds__(256) void gemm_out_kernel(
    const unsigned short* __restrict__ A, const unsigned short* __restrict__ Bt,
    float* __restrict__ Out, const float* __restrict__ bias) {
  __shared__ unsigned short As[8320];
  __shared__ unsigned short Bs[8320];
  f32x4 acc[4][4] = {};
  int l0 = blockIdx.x * 128, o0 = blockIdx.y * 128;
  gemm_acc128(A, Bt, l0, o0, acc, As, Bs);
  int lane = threadIdx.x & 63, wave = threadIdx.x >> 6;
  int wl = wave >> 1, wo = wave & 1, lg = lane >> 4, lr = lane & 15;
#pragma unroll
  for (int mf = 0; mf < 4; ++mf)
#pragma unroll
    for (int nf = 0; nf < 4; ++nf) {
      int row = l0 + wl * 64 + mf * 16 + 4 * lg;
      int col = o0 + wo * 64 + nf * 16 + lr;
      int b = row >> 11, n = row & 2047;
      float bv = bias[col];
      f32x4 v = acc[mf][nf];
#pragma unroll
      for (int r = 0; r < 4; ++r) v[r] += bv;
      *(f32x4*)&Out[((size_t)(b * 512 + col)) * 2048 + n] = v;
    }
}

// ---------------- flash attention R15: triple-buffer, ONE barrier per tile ----------------
// grid 1024 (XCD-bijective), block 256 = 4 waves (qg, kh); 32 tiles of 64 kv.
// K/V triple-buffered (50 KB): tile t+2 staged into buf (t+2)%3 while t is consumed.
// Safety: tile t-1 readers (same buffer) finished before barrier(t) (their lgkmcnt(0)
// precedes it), and STAGE(t+2) issues only after barrier(t) -> no WAR race.
// Counted vmcnt(4), raw s_barrier (1/tile), no-max softmax, HW cvt_pk,
// conflict-free lane-rotated kh-merge.
__global__ __launch_bounds__(256, 3) void attn_kernel(
    const unsigned short* __restrict__ Qb, const unsigned short* __restrict__ Kb,
    const unsigned short* __restrict__ Vt, unsigned short* __restrict__ Ob) {
  __shared__ unsigned short Ksh[3][4160];  // 8 groups x 1040 B per buf
  __shared__ unsigned short Vsh[3][4160];
  int id = blockIdx.x;
  int slot = id & 7, qb = (id >> 3) & 31, hbhi = id >> 8;
  int hb = hbhi * 8 + slot;
  int h = hb & 7, b = hb >> 3;
  int tid = threadIdx.x, w = tid >> 6, lane = tid & 63;
  int qg = w & 1, kh = w >> 1;
  int l31 = lane & 31, hi = lane >> 5;
  int qrow = b * 2048 + qb * 64 + qg * 32 + l31;

  // Q fragments (once)
  const unsigned short* qp = Qb + (size_t)qrow * 512 + h * 64 + 8 * hi;
  bf16x8 qf[4];
#pragma unroll
  for (int dk = 0; dk < 4; ++dk) qf[dk] = *(const bf16x8*)(qp + 16 * dk);

  // staging: wave w covers rows w*16..w*16+15 (groups 2w, 2w+1): 2 K + 2 V loads/tile
  int r8 = lane >> 3, gc = (lane & 7) ^ r8;  // pre-swizzled global chunk
  const unsigned short* kg =
      Kb + (size_t)(b * 2048 + w * 16 + r8) * 512 + h * 64 + gc * 8;
  const unsigned short* vg =
      Vt + (size_t)((b * 8 + h) * 64 + w * 16 + r8) * 2048 + gc * 8;
  int grp0 = w * 2;

#define STAGE(t, bi)                                                               \
  {                                                                                \
    _Pragma("unroll") for (int j2 = 0; j2 < 2; ++j2) {                             \
      __builtin_amdgcn_global_load_lds(                                            \
          (const __attribute__((address_space(1))) void*)(kg +                     \
              (size_t)((t) * 64 + j2 * 8) * 512),                                  \
          (__attribute__((address_space(3))) void*)(&Ksh[bi][(grp0 + j2) * 520]),  \
          16, 0, 0);                                                               \
      __builtin_amdgcn_global_load_lds(                                            \
          (const __attribute__((address_space(1))) void*)(vg +                     \
              (size_t)(j2 * 8) * 2048 + (t) * 64),                                 \
          (__attribute__((address_space(3))) void*)(&Vsh[bi][(grp0 + j2) * 520]),  \
          16, 0, 0);                                                               \
    }                                                                              \
  }

  STAGE(0, 0);
  STAGE(1, 1);

  // K frag rows: kv = kh*32 + l31 (this wave's kv-half)
  int rowK = kh * 32 + l31;
  int rowoffK = (rowK >> 3) * 1040 + (rowK & 7) * 128;
  // V frag rows: dv = l31 (o0) and 32+l31 (o1), kv chunks restricted to half kh
  int rowoff0 = (l31 >> 3) * 1040 + (l31 & 7) * 128;
  int rowoff1 = rowoff0 + 4 * 1040;
  int swz = (l31 & 7) << 4;

  f32x16 o0 = {}, o1 = {};
  float lsum = 0.0f;
  int bi = 0, bs = 2;  // bi: buffer of tile t; bs: buffer for tile t+2

#pragma unroll 1
  for (int t = 0; t < 32; ++t) {
    if (t == 31) { asm volatile("s_waitcnt vmcnt(0)" ::: "memory"); }
    else         { asm volatile("s_waitcnt vmcnt(4)" ::: "memory"); }
    __builtin_amdgcn_sched_barrier(0);
    __builtin_amdgcn_s_barrier();  // tile t staged & visible; tile t-1 reads all retired
    __builtin_amdgcn_sched_barrier(0);

    const char* kbC = (const char*)&Ksh[bi][0];
    const char* vbC = (const char*)&Vsh[bi][0];
    bf16x8 kfr[4];
#pragma unroll
    for (int dk = 0; dk < 4; ++dk)
      kfr[dk] = *(const bf16x8*)(kbC + rowoffK + (((2 * dk + hi) << 4) ^ swz));
    bf16x8 vfa[2], vfb[2];
#pragma unroll
    for (int qq = 0; qq < 2; ++qq) {
      int ch = (2 * (2 * kh + qq) + hi) << 4;
      vfa[qq] = *(const bf16x8*)(vbC + rowoff0 + (ch ^ swz));
      vfb[qq] = *(const bf16x8*)(vbC + rowoff1 + (ch ^ swz));
    }
    asm volatile("s_waitcnt lgkmcnt(0)" ::: "memory");
    __builtin_amdgcn_sched_barrier(0);
    if (t < 30) STAGE(t + 2, bs);  // different buffer than bi; WAR-safe (see header)

    __builtin_amdgcn_s_setprio(1);
    f32x16 sA = {};
#pragma unroll
    for (int dk = 0; dk < 4; ++dk) sA = MFMA32(kfr[dk], qf[dk], sA);
    __builtin_amdgcn_s_setprio(0);

    // no-max softmax: P = exp2(s); lane-local sums
#pragma unroll
    for (int i = 0; i < 16; ++i) sA[i] = __builtin_amdgcn_exp2f(sA[i]);
    float u[8];
#pragma unroll
    for (int i = 0; i < 8; ++i) u[i] = sA[i] + sA[i + 8];
    lsum += ((u[0] + u[1]) + (u[2] + u[3])) + ((u[4] + u[5]) + (u[6] + u[7]));

    bf16x8 pt[2];
    {
      union { unsigned int wd[4]; bf16x8 v; } uu;
      uu.wd[0] = cvtpk(sA[0], sA[1]); uu.wd[1] = cvtpk(sA[2], sA[3]);
      uu.wd[2] = cvtpk(sA[4], sA[5]); uu.wd[3] = cvtpk(sA[6], sA[7]);
      pt[0] = uu.v;
      uu.wd[0] = cvtpk(sA[8], sA[9]); uu.wd[1] = cvtpk(sA[10], sA[11]);
      uu.wd[2] = cvtpk(sA[12], sA[13]); uu.wd[3] = cvtpk(sA[14], sA[15]);
      pt[1] = uu.v;
    }

    __builtin_amdgcn_s_setprio(1);
    o0 = MFMA32(vfa[0], pt[0], o0);
    o0 = MFMA32(vfa[1], pt[1], o0);
    o1 = MFMA32(vfb[0], pt[0], o1);
    o1 = MFMA32(vfb[1], pt[1], o1);
    __builtin_amdgcn_s_setprio(0);

    bi = (bi == 2) ? 0 : bi + 1;
    bs = (bs == 2) ? 0 : bs + 1;
  }
#undef STAGE

  // ---- merge kv-halves (no-max: pure add). Lane-rotated slots: conflict-free. ----
  float lt = lsum + __shfl_xor(lsum, 32, 64);
  __syncthreads();  // all loop LDS traffic retired; buffers reusable
  float* mo = (float*)&Ksh[0][0];   // [qg*64+lane][32] rotated (16 KB < 24.9 KB avail)
  float* mlp = (float*)&Vsh[0][0];  // lsum publish: [qg*64+lane]
  if (kh == 1) {
    float* d = mo + (qg * 64 + lane) * 32;
#pragma unroll
    for (int i = 0; i < 16; ++i) {
      d[(i + lane) & 31] = o0[i];
      d[(16 + i + lane) & 31] = o1[i];
    }
    mlp[qg * 64 + lane] = lt;
  }
  __syncthreads();
  if (kh == 0) {
    const float* d = mo + (qg * 64 + lane) * 32;
    float ltot = lt + mlp[qg * 64 + lane];
    float rinv = 1.0f / ltot;
    unsigned short* ob = Ob + (size_t)qrow * 512 + h * 64 + 4 * hi;
#pragma unroll
    for (int i = 0; i < 8; ++i) {
      int dvlo = ((2 * i) & 3) + 8 * ((2 * i) >> 2);
      float a0 = (o0[2 * i] + d[(2 * i + lane) & 31]) * rinv;
      float a1 = (o0[2 * i + 1] + d[(2 * i + 1 + lane) & 31]) * rinv;
      *(unsigned int*)(ob + dvlo) = cvtpk(a0, a1);
      float b0v = (o1[2 * i] + d[(16 + 2 * i + lane) & 31]) * rinv;
      float b1v = (o1[2 * i + 1] + d[(16 + 2 * i + 1 + lane) & 31]) * rinv;
      *(unsigned int*)(ob + 32 + dvlo) = cvtpk(b0v, b1v);
    }
  }
}

// ---------------- launcher ----------------
extern "C" void kernel_launch(void* const* d_in, const int* in_sizes, int n_in,
                              void* d_out, int out_size, void* d_ws, size_t ws_size,
                              hipStream_t stream) {
  const float* x   = (const float*)d_in[0];
  const float* ctx = (const float*)d_in[1];
  const float* Wq  = (const float*)d_in[2];
  const float* Wkv = (const float*)d_in[3];
  const float* Wo  = (const float*)d_in[4];
  const float* bo  = (const float*)d_in[5];
  float* out = (float*)d_out;

  char* ws = (char*)d_ws;
  unsigned short* xt   = (unsigned short*)(ws + 0);
  unsigned short* ct   = (unsigned short*)(ws + 8388608);
  unsigned short* Wqt  = (unsigned short*)(ws + 16777216);
  unsigned short* Wkvt = (unsigned short*)(ws + 17301504);
  unsigned short* Wot  = (unsigned short*)(ws + 18350080);
  unsigned short* Qb   = (unsigned short*)(ws + 18874368);
  unsigned short* Kb   = (unsigned short*)(ws + 27262976);
  unsigned short* Vtb  = (unsigned short*)(ws + 35651584);
  unsigned short* Ob   = (unsigned short*)(ws + 44040192);

  transpose_all_kernel<<<dim3(64, 8, 11), 256, 0, stream>>>(
      x, ctx, Wq, Wkv, Wo, xt, ct, Wqt, Wkvt, Wot);

  gemm_qkv_kernel<<<dim3(64, 12), 256, 0, stream>>>(xt, ct, Wqt, Wkvt, Qb, Kb, Vtb);

  attn_kernel<<<dim3(1024), 256, 0, stream>>>(Qb, Kb, Vtb, Ob);

  gemm_out_kernel<<<dim3(64, 4), 256, 0, stream>>>(Ob, Wot, out, bo);
}

// Round 16
// 94.757 us; speedup vs baseline: 1.0514x; 1.0514x over previous
//
#include <hip/hip_runtime.h>
#include <hip/hip_bf16.h>

typedef __attribute__((ext_vector_type(8))) short bf16x8;
typedef __attribute__((ext_vector_type(4))) float f32x4;
typedef __attribute__((ext_vector_type(16))) float f32x16;
typedef __attribute__((ext_vector_type(8))) unsigned short ushort8v;
typedef __attribute__((ext_vector_type(4))) unsigned short ushort4v;

#define MFMA16(a, b, c) __builtin_amdgcn_mfma_f32_16x16x32_bf16((a), (b), (c), 0, 0, 0)
#define MFMA32(a, b, c) __builtin_amdgcn_mfma_f32_32x32x16_bf16((a), (b), (c), 0, 0, 0)

// HW packed f32->bf16 (src0 -> low16, src1 -> high16, RNE)
__device__ __forceinline__ unsigned int cvtpk(float a, float b) {
  unsigned int r;
  asm("v_cvt_pk_bf16_f32 %0, %1, %2" : "=v"(r) : "v"(a), "v"(b));
  return r;
}
__device__ __forceinline__ unsigned short f2bf(float f) {
  return (unsigned short)cvtpk(f, f);
}

// ---------------- all transposes in one kernel ----------------
__global__ __launch_bounds__(256) void transpose_all_kernel(
    const float* __restrict__ x, const float* __restrict__ ctx,
    const float* __restrict__ Wq, const float* __restrict__ Wkv,
    const float* __restrict__ Wo, unsigned short* __restrict__ xt,
    unsigned short* __restrict__ ct, unsigned short* __restrict__ Wqt,
    unsigned short* __restrict__ Wkvt, unsigned short* __restrict__ Wot) {
  __shared__ float tile[64][33];
  int z = blockIdx.z;
  const float* in;
  unsigned short* out;
  int C;
  if (z < 4)      { in = x + (size_t)z * 512 * 2048;         out = xt + (size_t)z * 2048 * 512;        C = 2048; }
  else if (z < 8) { in = ctx + (size_t)(z - 4) * 512 * 2048; out = ct + (size_t)(z - 4) * 2048 * 512;  C = 2048; }
  else if (z == 8) { in = Wq;  out = Wqt;  C = 512; }
  else if (z == 9) { in = Wkv; out = Wkvt; C = 1024; }
  else             { in = Wo;  out = Wot;  C = 512; }
  int c0 = blockIdx.x * 32;
  if (c0 >= C) return;
  int r0 = blockIdx.y * 64;
  int tid = threadIdx.x, cl = tid & 31, rl = tid >> 5;
#pragma unroll
  for (int k = 0; k < 8; ++k)
    tile[rl + 8 * k][cl] = in[(size_t)(r0 + rl + 8 * k) * C + c0 + cl];
  __syncthreads();
  int c = tid >> 3, rc = (tid & 7) * 8;
  union { unsigned int wd[4]; ushort8v v; } p;
#pragma unroll
  for (int jj = 0; jj < 4; ++jj)
    p.wd[jj] = cvtpk(tile[rc + 2 * jj][c], tile[rc + 2 * jj + 1][c]);
  *(ushort8v*)&out[(size_t)(c0 + c) * 512 + r0 + rc] = p.v;
}

// ---------------- shared NT-GEMM core, 128x128 tile, global_load_lds staging ----------------
__device__ __forceinline__ void gemm_acc128(
    const unsigned short* __restrict__ A, const unsigned short* __restrict__ Bt,
    int l0, int o0, f32x4 acc[4][4],
    unsigned short* As, unsigned short* Bs) {
  int tid = threadIdx.x, lane = tid & 63, wv = tid >> 6;
  int wl = wv >> 1, wo = wv & 1, lg = lane >> 4, lr = lane & 15;
  int r8 = lane >> 3, gc = (lane & 7) ^ r8;
  const unsigned short* ga = A + (size_t)(l0 + wv * 32 + r8) * 512 + gc * 8;
  const unsigned short* gb = Bt + (size_t)(o0 + wv * 32 + r8) * 512 + gc * 8;
  int rowbA[4], rswA[4], rowbB[4], rswB[4];
#pragma unroll
  for (int f = 0; f < 4; ++f) {
    int r = wl * 64 + f * 16 + lr;
    rowbA[f] = (r >> 3) * 1040 + (r & 7) * 128;
    rswA[f] = (r & 7) << 4;
    int rb = wo * 64 + f * 16 + lr;
    rowbB[f] = (rb >> 3) * 1040 + (rb & 7) * 128;
    rswB[f] = (rb & 7) << 4;
  }
  const char* aC = (const char*)As;
  const char* bC = (const char*)Bs;
  for (int kb = 0; kb < 512; kb += 64) {
#pragma unroll
    for (int j = 0; j < 4; ++j) {
      __builtin_amdgcn_global_load_lds(
          (const __attribute__((address_space(1))) void*)(ga + (size_t)(j * 8) * 512 + kb),
          (__attribute__((address_space(3))) void*)(As + (wv * 4 + j) * 520), 16, 0, 0);
      __builtin_amdgcn_global_load_lds(
          (const __attribute__((address_space(1))) void*)(gb + (size_t)(j * 8) * 512 + kb),
          (__attribute__((address_space(3))) void*)(Bs + (wv * 4 + j) * 520), 16, 0, 0);
    }
    __syncthreads();
#pragma unroll
    for (int kc = 0; kc < 2; ++kc) {
      bf16x8 af[4], bfr[4];
#pragma unroll
      for (int mf = 0; mf < 4; ++mf)
        af[mf] = *(const bf16x8*)(aC + rowbA[mf] + (((4 * kc + lg) << 4) ^ rswA[mf]));
#pragma unroll
      for (int nf = 0; nf < 4; ++nf)
        bfr[nf] = *(const bf16x8*)(bC + rowbB[nf] + (((4 * kc + lg) << 4) ^ rswB[nf]));
#pragma unroll
      for (int mf = 0; mf < 4; ++mf)
#pragma unroll
        for (int nf = 0; nf < 4; ++nf)
          acc[mf][nf] = MFMA16(af[mf], bfr[nf], acc[mf][nf]);
    }
    __syncthreads();
  }
}

// Merged Q + KV projection.
__global__ __launch_bounds__(256) void gemm_qkv_kernel(
    const unsigned short* __restrict__ xt, const unsigned short* __restrict__ ct,
    const unsigned short* __restrict__ Wqt, const unsigned short* __restrict__ Wkvt,
    unsigned short* __restrict__ Qb, unsigned short* __restrict__ K,
    unsigned short* __restrict__ Vt) {
  __shared__ unsigned short As[8320];
  __shared__ unsigned short Bs[8320];
  f32x4 acc[4][4] = {};
  int l0 = blockIdx.x * 128;
  int yy = blockIdx.y;
  const unsigned short* A;
  const unsigned short* Bt;
  int o0;
  if (yy < 4) { A = xt; Bt = Wqt; o0 = yy * 128; }
  else        { A = ct; Bt = Wkvt; o0 = (yy - 4) * 128; }
  gemm_acc128(A, Bt, l0, o0, acc, As, Bs);
  int lane = threadIdx.x & 63, wave = threadIdx.x >> 6;
  int wl = wave >> 1, wo = wave & 1, lg = lane >> 4, lr = lane & 15;
  if (yy < 4) {
    const float qs = 0.18033688011112042f;  // 0.125 * log2(e)
#pragma unroll
    for (int mf = 0; mf < 4; ++mf)
#pragma unroll
      for (int nf = 0; nf < 4; ++nf)
#pragma unroll
        for (int r = 0; r < 4; ++r) {
          int row = l0 + wl * 64 + mf * 16 + 4 * lg + r;
          int col = o0 + wo * 64 + nf * 16 + lr;
          Qb[(size_t)row * 512 + col] = f2bf(acc[mf][nf][r] * qs);
        }
  } else if (o0 < 512) {
#pragma unroll
    for (int mf = 0; mf < 4; ++mf)
#pragma unroll
      for (int nf = 0; nf < 4; ++nf)
#pragma unroll
        for (int r = 0; r < 4; ++r) {
          int row = l0 + wl * 64 + mf * 16 + 4 * lg + r;
          int col = o0 + wo * 64 + nf * 16 + lr;
          K[(size_t)row * 512 + col] = f2bf(acc[mf][nf][r]);
        }
  } else {
    int b = l0 >> 11;
#pragma unroll
    for (int mf = 0; mf < 4; ++mf)
#pragma unroll
      for (int nf = 0; nf < 4; ++nf) {
        int m0v = (l0 & 2047) + wl * 64 + mf * 16 + 4 * lg;
        int msw = (m0v & ~12) | ((m0v & 4) << 1) | ((m0v & 8) >> 1);  // swap bits 2,3
        int oh = (o0 - 512) + wo * 64 + nf * 16 + lr;
        int h = oh >> 6, d = oh & 63;
        ushort4v pk;
#pragma unroll
        for (int r = 0; r < 4; ++r) pk[r] = f2bf(acc[mf][nf][r]);
        *(ushort4v*)&Vt[(size_t)((b * 8 + h) * 64 + d) * 2048 + msw] = pk;
      }
  }
}

// Out projection: 64x128 tile (grid 128x4 = 512 blocks = 2/CU for latency hiding).
__global__ __launch_bounds__(256) void gemm_out_kernel(
    const unsigned short* __restrict__ A, const unsigned short* __restrict__ Bt,
    float* __restrict__ Out, const float* __restrict__ bias) {
  __shared__ unsigned short As[4160];  // 64 rows: 8 groups x 520
  __shared__ unsigned short Bs[8320];  // 128 rows: 16 groups x 520
  f32x4 acc[2][4] = {};
  int l0 = blockIdx.x * 64, o0 = blockIdx.y * 128;
  int tid = threadIdx.x, lane = tid & 63, wv = tid >> 6;
  int wl = wv >> 1, wo = wv & 1, lg = lane >> 4, lr = lane & 15;
  int r8 = lane >> 3, gc = (lane & 7) ^ r8;
  const unsigned short* ga = A + (size_t)(l0 + wv * 16 + r8) * 512 + gc * 8;
  const unsigned short* gb = Bt + (size_t)(o0 + wv * 32 + r8) * 512 + gc * 8;
  int rowbA[2], rswA[2], rowbB[4], rswB[4];
#pragma unroll
  for (int f = 0; f < 2; ++f) {
    int r = wl * 32 + f * 16 + lr;
    rowbA[f] = (r >> 3) * 1040 + (r & 7) * 128;
    rswA[f] = (r & 7) << 4;
  }
#pragma unroll
  for (int f = 0; f < 4; ++f) {
    int rb = wo * 64 + f * 16 + lr;
    rowbB[f] = (rb >> 3) * 1040 + (rb & 7) * 128;
    rswB[f] = (rb & 7) << 4;
  }
  const char* aC = (const char*)As;
  const char* bC = (const char*)Bs;
  for (int kb = 0; kb < 512; kb += 64) {
#pragma unroll
    for (int j = 0; j < 2; ++j)
      __builtin_amdgcn_global_load_lds(
          (const __attribute__((address_space(1))) void*)(ga + (size_t)(j * 8) * 512 + kb),
          (__attribute__((address_space(3))) void*)(As + (wv * 2 + j) * 520), 16, 0, 0);
#pragma unroll
    for (int j = 0; j < 4; ++j)
      __builtin_amdgcn_global_load_lds(
          (const __attribute__((address_space(1))) void*)(gb + (size_t)(j * 8) * 512 + kb),
          (__attribute__((address_space(3))) void*)(Bs + (wv * 4 + j) * 520), 16, 0, 0);
    __syncthreads();
#pragma unroll
    for (int kc = 0; kc < 2; ++kc) {
      bf16x8 af[2], bfr[4];
#pragma unroll
      for (int mf = 0; mf < 2; ++mf)
        af[mf] = *(const bf16x8*)(aC + rowbA[mf] + (((4 * kc + lg) << 4) ^ rswA[mf]));
#pragma unroll
      for (int nf = 0; nf < 4; ++nf)
        bfr[nf] = *(const bf16x8*)(bC + rowbB[nf] + (((4 * kc + lg) << 4) ^ rswB[nf]));
#pragma unroll
      for (int mf = 0; mf < 2; ++mf)
#pragma unroll
        for (int nf = 0; nf < 4; ++nf)
          acc[mf][nf] = MFMA16(af[mf], bfr[nf], acc[mf][nf]);
    }
    __syncthreads();
  }
#pragma unroll
  for (int mf = 0; mf < 2; ++mf)
#pragma unroll
    for (int nf = 0; nf < 4; ++nf) {
      int row = l0 + wl * 32 + mf * 16 + 4 * lg;
      int col = o0 + wo * 64 + nf * 16 + lr;
      int b = row >> 11, n = row & 2047;
      float bv = bias[col];
      f32x4 v = acc[mf][nf];
#pragma unroll
      for (int r = 0; r < 4; ++r) v[r] += bv;
      *(f32x4*)&Out[((size_t)(b * 512 + col)) * 2048 + n] = v;
    }
}

// ---------------- flash attention R14 (best: 49.8 us): dbuf, 2 barriers/tile ----------------
__global__ __launch_bounds__(256, 4) void attn_kernel(
    const unsigned short* __restrict__ Qb, const unsigned short* __restrict__ Kb,
    const unsigned short* __restrict__ Vt, unsigned short* __restrict__ Ob) {
  __shared__ unsigned short Ksh[2][4160];  // 8 groups x 1040 B
  __shared__ unsigned short Vsh[2][4160];
  int id = blockIdx.x;
  int slot = id & 7, qb = (id >> 3) & 31, hbhi = id >> 8;
  int hb = hbhi * 8 + slot;
  int h = hb & 7, b = hb >> 3;
  int tid = threadIdx.x, w = tid >> 6, lane = tid & 63;
  int qg = w & 1, kh = w >> 1;
  int l31 = lane & 31, hi = lane >> 5;
  int qrow = b * 2048 + qb * 64 + qg * 32 + l31;

  // Q fragments (once)
  const unsigned short* qp = Qb + (size_t)qrow * 512 + h * 64 + 8 * hi;
  bf16x8 qf[4];
#pragma unroll
  for (int dk = 0; dk < 4; ++dk) qf[dk] = *(const bf16x8*)(qp + 16 * dk);

  // staging: wave w covers rows w*16..w*16+15 (groups 2w, 2w+1): 2 K + 2 V loads/tile
  int r8 = lane >> 3, gc = (lane & 7) ^ r8;  // pre-swizzled global chunk
  const unsigned short* kg =
      Kb + (size_t)(b * 2048 + w * 16 + r8) * 512 + h * 64 + gc * 8;
  const unsigned short* vg =
      Vt + (size_t)((b * 8 + h) * 64 + w * 16 + r8) * 2048 + gc * 8;
  int grp0 = w * 2;

#define STAGE(t, bi)                                                               \
  {                                                                                \
    _Pragma("unroll") for (int j2 = 0; j2 < 2; ++j2) {                             \
      __builtin_amdgcn_global_load_lds(                                            \
          (const __attribute__((address_space(1))) void*)(kg +                     \
              (size_t)((t) * 64 + j2 * 8) * 512),                                  \
          (__attribute__((address_space(3))) void*)(&Ksh[bi][(grp0 + j2) * 520]),  \
          16, 0, 0);                                                               \
      __builtin_amdgcn_global_load_lds(                                            \
          (const __attribute__((address_space(1))) void*)(vg +                     \
              (size_t)(j2 * 8) * 2048 + (t) * 64),                                 \
          (__attribute__((address_space(3))) void*)(&Vsh[bi][(grp0 + j2) * 520]),  \
          16, 0, 0);                                                               \
    }                                                                              \
  }

  STAGE(0, 0);
  STAGE(1, 1);

  // K frag rows: kv = kh*32 + l31 (this wave's kv-half)
  int rowK = kh * 32 + l31;
  int rowoffK = (rowK >> 3) * 1040 + (rowK & 7) * 128;
  // V frag rows: dv = l31 (o0) and 32+l31 (o1), kv chunks restricted to half kh
  int rowoff0 = (l31 >> 3) * 1040 + (l31 & 7) * 128;
  int rowoff1 = rowoff0 + 4 * 1040;
  int swz = (l31 & 7) << 4;

  f32x16 o0 = {}, o1 = {};
  float lsum = 0.0f;

#pragma unroll 1
  for (int t = 0; t < 32; ++t) {
    int bi = t & 1;
    if (t == 31) { asm volatile("s_waitcnt vmcnt(0)" ::: "memory"); }
    else         { asm volatile("s_waitcnt vmcnt(4)" ::: "memory"); }
    __builtin_amdgcn_sched_barrier(0);
    __builtin_amdgcn_s_barrier();  // staged tile bi visible to all 4 waves
    __builtin_amdgcn_sched_barrier(0);

    const char* kbC = (const char*)&Ksh[bi][0];
    const char* vbC = (const char*)&Vsh[bi][0];
    bf16x8 kfr[4];
#pragma unroll
    for (int dk = 0; dk < 4; ++dk)
      kfr[dk] = *(const bf16x8*)(kbC + rowoffK + (((2 * dk + hi) << 4) ^ swz));
    bf16x8 vfa[2], vfb[2];
#pragma unroll
    for (int qq = 0; qq < 2; ++qq) {
      int ch = (2 * (2 * kh + qq) + hi) << 4;
      vfa[qq] = *(const bf16x8*)(vbC + rowoff0 + (ch ^ swz));
      vfb[qq] = *(const bf16x8*)(vbC + rowoff1 + (ch ^ swz));
    }
    asm volatile("s_waitcnt lgkmcnt(0)" ::: "memory");
    __builtin_amdgcn_sched_barrier(0);
    __builtin_amdgcn_s_barrier();  // reads retired -> buffer bi overwritable
    __builtin_amdgcn_sched_barrier(0);
    if (t < 30) STAGE(t + 2, bi);

    __builtin_amdgcn_s_setprio(1);
    f32x16 sA = {};
#pragma unroll
    for (int dk = 0; dk < 4; ++dk) sA = MFMA32(kfr[dk], qf[dk], sA);
    __builtin_amdgcn_s_setprio(0);

    // no-max softmax: P = exp2(s); lane-local sums
#pragma unroll
    for (int i = 0; i < 16; ++i) sA[i] = __builtin_amdgcn_exp2f(sA[i]);
    float u[8];
#pragma unroll
    for (int i = 0; i < 8; ++i) u[i] = sA[i] + sA[i + 8];
    lsum += ((u[0] + u[1]) + (u[2] + u[3])) + ((u[4] + u[5]) + (u[6] + u[7]));

    bf16x8 pt[2];
    {
      union { unsigned int wd[4]; bf16x8 v; } uu;
      uu.wd[0] = cvtpk(sA[0], sA[1]); uu.wd[1] = cvtpk(sA[2], sA[3]);
      uu.wd[2] = cvtpk(sA[4], sA[5]); uu.wd[3] = cvtpk(sA[6], sA[7]);
      pt[0] = uu.v;
      uu.wd[0] = cvtpk(sA[8], sA[9]); uu.wd[1] = cvtpk(sA[10], sA[11]);
      uu.wd[2] = cvtpk(sA[12], sA[13]); uu.wd[3] = cvtpk(sA[14], sA[15]);
      pt[1] = uu.v;
    }

    __builtin_amdgcn_s_setprio(1);
    o0 = MFMA32(vfa[0], pt[0], o0);
    o0 = MFMA32(vfa[1], pt[1], o0);
    o1 = MFMA32(vfb[0], pt[0], o1);
    o1 = MFMA32(vfb[1], pt[1], o1);
    __builtin_amdgcn_s_setprio(0);
  }
#undef STAGE

  // ---- merge kv-halves (no-max: pure add). Lane-rotated slots: conflict-free. ----
  float lt = lsum + __shfl_xor(lsum, 32, 64);
  __syncthreads();  // all loop LDS traffic retired; buffers reusable
  float* mo = (float*)&Ksh[0][0];   // [qg*64+lane][32] rotated
  float* mlp = (float*)&Vsh[0][0];  // lsum publish: [qg*64+lane]
  if (kh == 1) {
    float* d = mo + (qg * 64 + lane) * 32;
#pragma unroll
    for (int i = 0; i < 16; ++i) {
      d[(i + lane) & 31] = o0[i];
      d[(16 + i + lane) & 31] = o1[i];
    }
    mlp[qg * 64 + lane] = lt;
  }
  __syncthreads();
  if (kh == 0) {
    const float* d = mo + (qg * 64 + lane) * 32;
    float ltot = lt + mlp[qg * 64 + lane];
    float rinv = 1.0f / ltot;
    unsigned short* ob = Ob + (size_t)qrow * 512 + h * 64 + 4 * hi;
#pragma unroll
    for (int i = 0; i < 8; ++i) {
      int dvlo = ((2 * i) & 3) + 8 * ((2 * i) >> 2);
      float a0 = (o0[2 * i] + d[(2 * i + lane) & 31]) * rinv;
      float a1 = (o0[2 * i + 1] + d[(2 * i + 1 + lane) & 31]) * rinv;
      *(unsigned int*)(ob + dvlo) = cvtpk(a0, a1);
      float b0v = (o1[2 * i] + d[(16 + 2 * i + lane) & 31]) * rinv;
      float b1v = (o1[2 * i + 1] + d[(16 + 2 * i + 1 + lane) & 31]) * rinv;
      *(unsigned int*)(ob + 32 + dvlo) = cvtpk(b0v, b1v);
    }
  }
}

// ---------------- launcher ----------------
extern "C" void kernel_launch(void* const* d_in, const int* in_sizes, int n_in,
                              void* d_out, int out_size, void* d_ws, size_t ws_size,
                              hipStream_t stream) {
  const float* x   = (const float*)d_in[0];
  const float* ctx = (const float*)d_in[1];
  const float* Wq  = (const float*)d_in[2];
  const float* Wkv = (const float*)d_in[3];
  const float* Wo  = (const float*)d_in[4];
  const float* bo  = (const float*)d_in[5];
  float* out = (float*)d_out;

  char* ws = (char*)d_ws;
  unsigned short* xt   = (unsigned short*)(ws + 0);
  unsigned short* ct   = (unsigned short*)(ws + 8388608);
  unsigned short* Wqt  = (unsigned short*)(ws + 16777216);
  unsigned short* Wkvt = (unsigned short*)(ws + 17301504);
  unsigned short* Wot  = (unsigned short*)(ws + 18350080);
  unsigned short* Qb   = (unsigned short*)(ws + 18874368);
  unsigned short* Kb   = (unsigned short*)(ws + 27262976);
  unsigned short* Vtb  = (unsigned short*)(ws + 35651584);
  unsigned short* Ob   = (unsigned short*)(ws + 44040192);

  transpose_all_kernel<<<dim3(64, 8, 11), 256, 0, stream>>>(
      x, ctx, Wq, Wkv, Wo, xt, ct, Wqt, Wkvt, Wot);

  gemm_qkv_kernel<<<dim3(64, 12), 256, 0, stream>>>(xt, ct, Wqt, Wkvt, Qb, Kb, Vtb);

  attn_kernel<<<dim3(1024), 256, 0, stream>>>(Qb, Kb, Vtb, Ob);

  gemm_out_kernel<<<dim3(128, 4), 256, 0, stream>>>(Ob, Wot, out, bo);
}